// Round 1
// baseline (144.653 us; speedup 1.0000x reference)
//
#include <hip/hip_runtime.h>
#include <hip/hip_bf16.h>
#include <stdint.h>

// Problem constants
#define B_SZ 4
#define T_LEN 8192
#define D_DIM 512
#define M_TOT (B_SZ * T_LEN)  // 32768
#define NCHUNK 128            // chunks along T
#define CLEN 64               // T / NCHUNK

typedef __attribute__((ext_vector_type(8))) short bf16x8v;  // 8 bf16 = 4 VGPRs
typedef __attribute__((ext_vector_type(4))) float f32x4v;

__device__ __forceinline__ unsigned short f2bf(float f) {
  // round-to-nearest-even bf16 (no NaN handling needed for this data)
  unsigned int u = __float_as_uint(f);
  u += 0x7fffu + ((u >> 16) & 1u);
  return (unsigned short)(u >> 16);
}

__device__ __forceinline__ float sigmoidf_(float x) {
  return 1.0f / (1.0f + expf(-x));
}

// ---------------------------------------------------------------------------
// Convert both weight matrices to bf16 into workspace.
__global__ void cvt_w_k(const float* __restrict__ Wb, const float* __restrict__ Wc,
                        unsigned short* __restrict__ o) {
  int i = blockIdx.x * 256 + threadIdx.x;  // grid 1024 x 256 == 262144 == 512*512
  o[i] = f2bf(Wb[i]);
  o[262144 + i] = f2bf(Wc[i]);
}

// ---------------------------------------------------------------------------
// C[M][512] = A[M][512] * W[512][512]^T   (C[m][n] = sum_k A[m][k] * W[n][k])
// ABF==0: A is f32 (converted to bf16 during staging). ABF==1: A is bf16.
// 128x128 tile, BK=64, 4 waves (2x2), each wave 64x64 via 4x4 16x16x32 MFMAs.
// LDS XOR-swizzle (byte ^= (row&7)<<4) on both write and read (G4 / T2).
template <int ABF>
__global__ __launch_bounds__(256) void gemm_bt(const void* __restrict__ Aptr,
                                               const unsigned short* __restrict__ Bw,
                                               float* __restrict__ C) {
  constexpr int K = 512, N = 512, BM = 128;
  __shared__ unsigned short As[BM * 64];
  __shared__ unsigned short Bs[BM * 64];
  const int tid = threadIdx.x;
  const int lane = tid & 63;
  const int wave = tid >> 6;
  const int wm = (wave >> 1) * 64;
  const int wn = (wave & 1) * 64;
  const int bm = blockIdx.y * BM;
  const int bn = blockIdx.x * BM;
  const int l15 = lane & 15;
  const int lq16 = (lane >> 4) * 16;  // byte offset of this lane's k-oct

  f32x4v acc[4][4] = {};

  for (int k0 = 0; k0 < K; k0 += 64) {
    if (ABF == 0) {
      const float* A = (const float*)Aptr;
      // 128 rows x 16 float4-units; 256 thr -> 8 iters; convert f32->bf16
#pragma unroll
      for (int it = 0; it < 8; ++it) {
        int idx = it * 256 + tid;
        int row = idx >> 4;
        int u = idx & 15;
        float4 v = *(const float4*)(&A[(size_t)(bm + row) * K + k0 + u * 4]);
        unsigned int lo = (unsigned int)f2bf(v.x) | ((unsigned int)f2bf(v.y) << 16);
        unsigned int hi = (unsigned int)f2bf(v.z) | ((unsigned int)f2bf(v.w) << 16);
        int byte = (row * 128 + u * 8) ^ ((row & 7) << 4);
        *(uint2*)((char*)As + byte) = make_uint2(lo, hi);
      }
    } else {
      const unsigned short* A = (const unsigned short*)Aptr;
      // 128 rows x 8 16B-units; 4 iters
#pragma unroll
      for (int it = 0; it < 4; ++it) {
        int idx = it * 256 + tid;
        int row = idx >> 3;
        int u = idx & 7;
        uint4 v = *(const uint4*)(&A[(size_t)(bm + row) * K + k0 + u * 8]);
        int byte = (row * 128 + u * 16) ^ ((row & 7) << 4);
        *(uint4*)((char*)As + byte) = v;
      }
    }
    // Stage W tile (bf16): rows are output cols n, contiguous in k.
#pragma unroll
    for (int it = 0; it < 4; ++it) {
      int idx = it * 256 + tid;
      int row = idx >> 3;
      int u = idx & 7;
      uint4 v = *(const uint4*)(&Bw[(size_t)(bn + row) * K + k0 + u * 8]);
      int byte = (row * 128 + u * 16) ^ ((row & 7) << 4);
      *(uint4*)((char*)Bs + byte) = v;
    }
    __syncthreads();
#pragma unroll
    for (int ks = 0; ks < 2; ++ks) {
      bf16x8v af[4], bfr[4];
#pragma unroll
      for (int i = 0; i < 4; ++i) {
        int row = wm + i * 16 + l15;
        int byte = (row * 128 + ks * 64 + lq16) ^ ((row & 7) << 4);
        af[i] = *(const bf16x8v*)((const char*)As + byte);
      }
#pragma unroll
      for (int j = 0; j < 4; ++j) {
        int row = wn + j * 16 + l15;
        int byte = (row * 128 + ks * 64 + lq16) ^ ((row & 7) << 4);
        bfr[j] = *(const bf16x8v*)((const char*)Bs + byte);
      }
#pragma unroll
      for (int i = 0; i < 4; ++i)
#pragma unroll
        for (int j = 0; j < 4; ++j)
          acc[i][j] = __builtin_amdgcn_mfma_f32_16x16x32_bf16(af[i], bfr[j], acc[i][j], 0, 0, 0);
    }
    __syncthreads();
  }
  // Epilogue: D row = (lane>>4)*4 + r, col = lane&15 (m89-verified layout)
  const int lr4 = (lane >> 4) * 4;
#pragma unroll
  for (int i = 0; i < 4; ++i) {
#pragma unroll
    for (int j = 0; j < 4; ++j) {
      int col = bn + wn + j * 16 + l15;
#pragma unroll
      for (int r = 0; r < 4; ++r) {
        C[(size_t)(bm + wm + i * 16 + lr4 + r) * N + col] = acc[i][j][r];
      }
    }
  }
}

// ---------------------------------------------------------------------------
// Chunk-local scan, in place on b (f32, [B][T][D]). One block = one (batch,
// chunk); 512 threads = all channels -> coalesced 2KB per time step.
__global__ void scan_local_k(float* __restrict__ b, const float* __restrict__ Adec) {
  const int d = threadIdx.x;
  const int bi = blockIdx.x >> 7;  // / NCHUNK
  const int c = blockIdx.x & (NCHUNK - 1);
  const float a = sigmoidf_(Adec[d]);
  float* p = b + ((size_t)bi * T_LEN + c * CLEN) * D_DIM + d;
  float h = 0.f;
#pragma unroll 8
  for (int i = 0; i < CLEN; ++i) {
    float v = p[(size_t)i * D_DIM];
    h = fmaf(a, h, v);
    p[(size_t)i * D_DIM] = h;
  }
}

// Inter-chunk carries: carry[bi][c][d] = true h at end of chunk c-1.
__global__ void scan_carry_k(const float* __restrict__ b, const float* __restrict__ Adec,
                             float* __restrict__ carry) {
  const int d = threadIdx.x;
  const int bi = blockIdx.x;  // grid = B_SZ
  const float a = sigmoidf_(Adec[d]);
  float a2 = a * a, a4 = a2 * a2, a8 = a4 * a4, a16 = a8 * a8, a32 = a16 * a16;
  const float aC = a32 * a32;  // a^64
  float H = 0.f;
  carry[((size_t)bi * NCHUNK) * D_DIM + d] = 0.f;
#pragma unroll 8
  for (int c = 1; c < NCHUNK; ++c) {
    float Lend = b[((size_t)bi * T_LEN + c * CLEN - 1) * D_DIM + d];
    H = fmaf(aC, H, Lend);
    carry[((size_t)bi * NCHUNK + c) * D_DIM + d] = H;
  }
}

// Apply carries: h[t] = h_local[t] + a^(i+1) * carry; emit bf16.
__global__ void scan_fix_k(const float* __restrict__ b, const float* __restrict__ Adec,
                           const float* __restrict__ carry, unsigned short* __restrict__ h) {
  const int d = threadIdx.x;
  const int bi = blockIdx.x >> 7;
  const int c = blockIdx.x & (NCHUNK - 1);
  const float a = sigmoidf_(Adec[d]);
  const float H = carry[((size_t)bi * NCHUNK + c) * D_DIM + d];
  const size_t base = ((size_t)bi * T_LEN + c * CLEN) * D_DIM + d;
  float f = a;
#pragma unroll 8
  for (int i = 0; i < CLEN; ++i) {
    float v = fmaf(f, H, b[base + (size_t)i * D_DIM]);
    h[base + (size_t)i * D_DIM] = f2bf(v);
    f *= a;
  }
}

// ---------------------------------------------------------------------------
extern "C" void kernel_launch(void* const* d_in, const int* in_sizes, int n_in,
                              void* d_out, int out_size, void* d_ws, size_t ws_size,
                              hipStream_t stream) {
  const float* x = (const float*)d_in[0];
  const float* W_B = (const float*)d_in[1];
  const float* W_C = (const float*)d_in[2];
  const float* A = (const float*)d_in[3];
  float* out = (float*)d_out;
  char* ws = (char*)d_ws;

  // ws layout: [0,512K) Wb bf16 | [512K,1M) Wc bf16 | [1M,2M) carry f32 |
  //            [2M,34M) h bf16
  unsigned short* Wb_bf = (unsigned short*)ws;
  unsigned short* Wc_bf = Wb_bf + 512 * 512;
  float* carry = (float*)(ws + (1u << 20));
  unsigned short* h_bf = (unsigned short*)(ws + (2u << 20));

  cvt_w_k<<<1024, 256, 0, stream>>>(W_B, W_C, Wb_bf);

  dim3 gg(D_DIM / 128, M_TOT / 128);  // (4, 256)
  gemm_bt<0><<<gg, 256, 0, stream>>>(x, Wb_bf, out);  // b = x @ W_B^T (f32 in d_out)

  scan_local_k<<<B_SZ * NCHUNK, D_DIM, 0, stream>>>(out, A);
  scan_carry_k<<<B_SZ, D_DIM, 0, stream>>>(out, A, carry);
  scan_fix_k<<<B_SZ * NCHUNK, D_DIM, 0, stream>>>(out, A, carry, h_bf);

  gemm_bt<1><<<gg, 256, 0, stream>>>(h_bf, Wc_bf, out);  // out = h @ W_C^T
}